// Round 3
// baseline (418.353 us; speedup 1.0000x reference)
//
#include <hip/hip_runtime.h>
#include <cstdint>

typedef __attribute__((ext_vector_type(8))) short short8;
typedef __attribute__((ext_vector_type(4))) float f32x4;
typedef __attribute__((ext_vector_type(4))) uint32_t u32x4;

constexpr int SEQ   = 2048;
constexpr int INSZ  = 256;   // K
constexpr int OUTSZ = 256;

__device__ __forceinline__ ushort f2bf(float f) {
  union { float f; uint32_t u; } v; v.f = f;
  uint32_t u = v.u;
  return (ushort)((u + 0x7FFFu + ((u >> 16) & 1u)) >> 16);  // RNE
}
__device__ __forceinline__ uint32_t pk2(float a, float b) {
  return (uint32_t)f2bf(a) | ((uint32_t)f2bf(b) << 16);
}

// ---------------------------------------------------------------------------
// Kernel 1: W_b = U[idx[b]] @ V, bf16, stored in MFMA B-fragment order:
//   ushort index = b*65536 + k5*8192 + nb*512 + lane*8 + j
// where k5 = k>>5, nb = o>>4, lane = (o&15) + ((k>>3)&3)*16, j = k&7.
// A wave's B fragment (16x32 subtile) is ONE coalesced 1KB load.
// ---------------------------------------------------------------------------
__global__ __launch_bounds__(256) void synth_w(
    const float* __restrict__ U, const float* __restrict__ V,
    const int* __restrict__ idx, ushort* __restrict__ wsW)
{
  const int b   = blockIdx.y;
  const int kb  = blockIdx.x;     // 0..3 -> local k window [kb*64, kb*64+64)
  const int tid = threadIdx.x;
  const int ch  = idx[b];
  const float u0 = U[ch*4+0], u1 = U[ch*4+1], u2 = U[ch*4+2], u3 = U[ch*4+3];

  __shared__ ushort tile[64][260];   // [k_local][o], padded to spread banks

  // phase 1: coalesced V reads, compute W tile [64 k][256 o] into LDS
  const int o4    = (tid & 63) * 4;
  const int kbase = (tid >> 6) * 16;
  for (int kk = 0; kk < 16; ++kk) {
    const int k  = kbase + kk;
    const int gk = kb*64 + k;
    const float* vp = V + (size_t)gk*OUTSZ + o4;
    float4 a = *(const float4*)(vp);
    float4 c = *(const float4*)(vp + 65536);
    float4 d = *(const float4*)(vp + 131072);
    float4 e = *(const float4*)(vp + 196608);
    ushort4 pkv;
    pkv.x = f2bf(u0*a.x + u1*c.x + u2*d.x + u3*e.x);
    pkv.y = f2bf(u0*a.y + u1*c.y + u2*d.y + u3*e.y);
    pkv.z = f2bf(u0*a.z + u1*c.z + u2*d.z + u3*e.z);
    pkv.w = f2bf(u0*a.w + u1*c.w + u2*d.w + u3*e.w);
    *(ushort4*)(&tile[k][o4]) = pkv;
  }
  __syncthreads();

  // phase 2: transpose out of LDS into fragment-order chunks (coalesced 16B)
  for (int s = 0; s < 8; ++s) {
    const int c      = s*256 + tid;     // 0..2047 chunks in this (b,kb) region
    const int kshalf = c >> 10;         // 0..1  -> global k5 = 2*kb + kshalf
    const int nb     = (c >> 6) & 15;   // 0..15
    const int lane   = c & 63;          // fragment lane
    const int o      = nb*16 + (lane & 15);
    const int k0     = kshalf*32 + (lane >> 4)*8;   // local k of j=0
    uint4 pkv;
    pkv.x = (uint32_t)tile[k0+0][o] | ((uint32_t)tile[k0+1][o] << 16);
    pkv.y = (uint32_t)tile[k0+2][o] | ((uint32_t)tile[k0+3][o] << 16);
    pkv.z = (uint32_t)tile[k0+4][o] | ((uint32_t)tile[k0+5][o] << 16);
    pkv.w = (uint32_t)tile[k0+6][o] | ((uint32_t)tile[k0+7][o] << 16);
    uint4* dst = (uint4*)(wsW + (size_t)b*65536 + (size_t)(2*kb + kshalf)*8192
                              + nb*512 + lane*8);
    *dst = pkv;
  }
}

// ---------------------------------------------------------------------------
// Kernel 2: out[b, n0:n0+64, :] = x[b, n0:n0+64, :] @ W_b + bias[idx[b]]
// ZERO LDS, ZERO barriers. 4 waves split by output cols (64 each).
// A-fragments loaded DIRECT global->VGPR from x (f32, 128B-coalesced per
// 16-lane group), converted to bf16 in-register. B direct from fragment-order
// wsW (1KB coalesced, L2-resident). Loads of k5+1 pipeline under MFMAs of k5.
// ---------------------------------------------------------------------------
__global__ __launch_bounds__(256, 3) void lr_gemm(
    const float* __restrict__ x, const int* __restrict__ idx,
    const float* __restrict__ bias, const ushort* __restrict__ wsW,
    float* __restrict__ out)
{
  // XCD-aware swizzle (8192 = 8*1024): a batch's 32 blocks stay on one XCD
  const int wg  = blockIdx.x;
  const int swz = (wg & 7) * 1024 + (wg >> 3);
  const int b   = swz >> 5;       // 0..255
  const int n0  = (swz & 31) * 64;

  const int tid  = threadIdx.x;
  const int lane = tid & 63;
  const int wave = tid >> 6;      // owns cols [wave*64, wave*64+64)
  const int hi16 = lane >> 4;
  const int lo16 = lane & 15;

  // per-lane A base: row lo16 (of each 16-row group), k-offset hi16*8
  const float*  xa  = x + ((size_t)b*SEQ + n0 + lo16)*INSZ + hi16*8;
  const ushort* wbp = wsW + (size_t)b*65536 + wave*2048 + lane*8;

  f32x4 acc[4][4] = {};

  #pragma unroll
  for (int k5 = 0; k5 < 8; ++k5) {
    short8 bf[4], af[4];
    #pragma unroll
    for (int n = 0; n < 4; ++n)
      bf[n] = *(const short8*)(wbp + (size_t)k5*8192 + n*512);
    #pragma unroll
    for (int m = 0; m < 4; ++m) {
      const float* ap = xa + (size_t)m*16*INSZ + k5*32;
      float4 f0 = *(const float4*)(ap);
      float4 f1 = *(const float4*)(ap + 4);
      u32x4 pk;
      pk.x = pk2(f0.x, f0.y); pk.y = pk2(f0.z, f0.w);
      pk.z = pk2(f1.x, f1.y); pk.w = pk2(f1.z, f1.w);
      af[m] = __builtin_bit_cast(short8, pk);
    }
    #pragma unroll
    for (int m = 0; m < 4; ++m)
      #pragma unroll
      for (int n = 0; n < 4; ++n)
        acc[m][n] = __builtin_amdgcn_mfma_f32_16x16x32_bf16(af[m], bf[n], acc[m][n], 0, 0, 0);
  }

  // ---- epilogue: + bias, store f32
  const int ch = idx[b];
  const float* bb = bias + (size_t)ch*OUTSZ;
  float bv[4];
  #pragma unroll
  for (int n = 0; n < 4; ++n) bv[n] = bb[wave*64 + n*16 + lo16];

  float* outb = out + ((size_t)b*SEQ + n0)*OUTSZ;
  #pragma unroll
  for (int m = 0; m < 4; ++m) {
    const int rbase = m*16 + hi16*4;
    #pragma unroll
    for (int n = 0; n < 4; ++n) {
      const int col = wave*64 + n*16 + lo16;
      #pragma unroll
      for (int j = 0; j < 4; ++j) {
        outb[(size_t)(rbase + j)*OUTSZ + col] = acc[m][n][j] + bv[n];
      }
    }
  }
}

extern "C" void kernel_launch(void* const* d_in, const int* in_sizes, int n_in,
                              void* d_out, int out_size, void* d_ws, size_t ws_size,
                              hipStream_t stream) {
  const float* x    = (const float*)d_in[0];
  const int*   idx  = (const int*)d_in[1];
  const float* U    = (const float*)d_in[2];
  const float* V    = (const float*)d_in[3];
  const float* bias = (const float*)d_in[4];
  float* out  = (float*)d_out;
  ushort* wsW = (ushort*)d_ws;     // 256*65536*2 = 32 MiB

  synth_w<<<dim3(4, 256), 256, 0, stream>>>(U, V, idx, wsW);
  lr_gemm<<<8192, 256, 0, stream>>>(x, idx, bias, wsW, out);
}

// Round 5
// 248.313 us; speedup vs baseline: 1.6848x; 1.6848x over previous
//
#include <hip/hip_runtime.h>
#include <cstdint>

typedef __attribute__((ext_vector_type(8))) short short8;
typedef __attribute__((ext_vector_type(4))) float f32x4;

constexpr int SEQ   = 2048;
constexpr int INSZ  = 256;   // K
constexpr int OUTSZ = 256;

__device__ __forceinline__ ushort f2bf(float f) {
  union { float f; uint32_t u; } v; v.f = f;
  uint32_t u = v.u;
  return (ushort)((u + 0x7FFFu + ((u >> 16) & 1u)) >> 16);  // RNE
}
__device__ __forceinline__ uint32_t pk2(float a, float b) {
  return (uint32_t)f2bf(a) | ((uint32_t)f2bf(b) << 16);
}

// ---------------------------------------------------------------------------
// Kernel 1: W_b = U[idx[b]] @ V, bf16, stored in MFMA B-fragment order:
//   ushort index = b*65536 + k5*8192 + nb*512 + lane*8 + j
// where k5 = k>>5, nb = o>>4, lane = (o&15) + ((k>>3)&3)*16, j = k&7.
// A wave's B fragment (16x32 subtile) is ONE coalesced 1KB load.
// ---------------------------------------------------------------------------
__global__ __launch_bounds__(256) void synth_w(
    const float* __restrict__ U, const float* __restrict__ V,
    const int* __restrict__ idx, ushort* __restrict__ wsW)
{
  const int b   = blockIdx.y;
  const int kb  = blockIdx.x;     // 0..3 -> local k window [kb*64, kb*64+64)
  const int tid = threadIdx.x;
  const int ch  = idx[b];
  const float u0 = U[ch*4+0], u1 = U[ch*4+1], u2 = U[ch*4+2], u3 = U[ch*4+3];

  __shared__ ushort tile[64][260];   // [k_local][o], padded to spread banks

  const int o4    = (tid & 63) * 4;
  const int kbase = (tid >> 6) * 16;
  for (int kk = 0; kk < 16; ++kk) {
    const int k  = kbase + kk;
    const int gk = kb*64 + k;
    const float* vp = V + (size_t)gk*OUTSZ + o4;
    float4 a = *(const float4*)(vp);
    float4 c = *(const float4*)(vp + 65536);
    float4 d = *(const float4*)(vp + 131072);
    float4 e = *(const float4*)(vp + 196608);
    ushort4 pkv;
    pkv.x = f2bf(u0*a.x + u1*c.x + u2*d.x + u3*e.x);
    pkv.y = f2bf(u0*a.y + u1*c.y + u2*d.y + u3*e.y);
    pkv.z = f2bf(u0*a.z + u1*c.z + u2*d.z + u3*e.z);
    pkv.w = f2bf(u0*a.w + u1*c.w + u2*d.w + u3*e.w);
    *(ushort4*)(&tile[k][o4]) = pkv;
  }
  __syncthreads();

  for (int s = 0; s < 8; ++s) {
    const int c      = s*256 + tid;
    const int kshalf = c >> 10;
    const int nb     = (c >> 6) & 15;
    const int lane   = c & 63;
    const int o      = nb*16 + (lane & 15);
    const int k0     = kshalf*32 + (lane >> 4)*8;
    uint4 pkv;
    pkv.x = (uint32_t)tile[k0+0][o] | ((uint32_t)tile[k0+1][o] << 16);
    pkv.y = (uint32_t)tile[k0+2][o] | ((uint32_t)tile[k0+3][o] << 16);
    pkv.z = (uint32_t)tile[k0+4][o] | ((uint32_t)tile[k0+5][o] << 16);
    pkv.w = (uint32_t)tile[k0+6][o] | ((uint32_t)tile[k0+7][o] << 16);
    uint4* dst = (uint4*)(wsW + (size_t)b*65536 + (size_t)(2*kb + kshalf)*8192
                              + nb*512 + lane*8);
    *dst = pkv;
  }
}

// ---------------------------------------------------------------------------
// Kernel 2: out[b, n0:n0+64, :] = x[b, n0:n0+64, :] @ W_b + bias[idx[b]]
// Round-2 skeleton + (1) depth-2 software pipeline on B, (2) coalesced
// epilogue: acc bounced through LDS, one full 1KB row per wave store-instr.
// ---------------------------------------------------------------------------
union SmemT {
  ushort a[64*256];   // A tile bf16, swizzled (32 KB)
  float  e[32*260];   // epilogue bounce, padded stride (33280 B)
};

__global__ __launch_bounds__(256, 4) void lr_gemm(
    const float* __restrict__ x, const int* __restrict__ idx,
    const float* __restrict__ bias, const ushort* __restrict__ wsW,
    float* __restrict__ out)
{
  __shared__ SmemT sm;

  // XCD-aware swizzle (8192 = 8*1024): a batch's 32 blocks stay on one XCD
  const int wg  = blockIdx.x;
  const int swz = (wg & 7) * 1024 + (wg >> 3);
  const int b   = swz >> 5;
  const int n0  = (swz & 31) * 64;

  const int tid  = threadIdx.x;
  const int lane = tid & 63;
  const int wave = tid >> 6;      // owns cols [wave*64, wave*64+64)
  const int hi16 = lane >> 4;
  const int lo16 = lane & 15;

  const float*  xb  = x + ((size_t)b*SEQ + n0)*INSZ;
  const ushort* wbp = wsW + (size_t)b*65536 + wave*2048 + lane*8;

  // ---- pipeline prologue: issue B[k5=0] before A-stage (independent of LDS)
  short8 bcur[4], bnxt[4];
  #pragma unroll
  for (int n = 0; n < 4; ++n)
    bcur[n] = *(const short8*)(wbp + n*512);

  // ---- stage A: full 64x256 f32 tile -> bf16 swizzled LDS (once)
  #pragma unroll
  for (int it = 0; it < 8; ++it) {
    const int row = it*8 + (tid >> 5);
    const int c8  = tid & 31;
    const float* src = xb + (size_t)row*INSZ + c8*8;
    float4 f0 = *(const float4*)(src);
    float4 f1 = *(const float4*)(src + 4);
    uint4 pkv;
    pkv.x = pk2(f0.x, f0.y); pkv.y = pk2(f0.z, f0.w);
    pkv.z = pk2(f1.x, f1.y); pkv.w = pk2(f1.z, f1.w);
    *(uint4*)((char*)sm.a + row*512 + ((c8*16) ^ ((row & 7) << 4))) = pkv;
  }
  __syncthreads();

  f32x4 acc[4][4] = {};
  const int sx = (lo16 & 7) << 4;
  const char* aB = (const char*)sm.a + lo16*512;

  #pragma unroll
  for (int k5 = 0; k5 < 8; ++k5) {
    if (k5 < 7) {
      #pragma unroll
      for (int n = 0; n < 4; ++n)
        bnxt[n] = *(const short8*)(wbp + (size_t)(k5+1)*8192 + n*512);
    }
    short8 af[4];
    #pragma unroll
    for (int m = 0; m < 4; ++m)
      af[m] = *(const short8*)(aB + m*8192 + ((k5*64 + hi16*16) ^ sx));
    #pragma unroll
    for (int m = 0; m < 4; ++m)
      #pragma unroll
      for (int n = 0; n < 4; ++n)
        acc[m][n] = __builtin_amdgcn_mfma_f32_16x16x32_bf16(af[m], bcur[n], acc[m][n], 0, 0, 0);
    #pragma unroll
    for (int n = 0; n < 4; ++n) bcur[n] = bnxt[n];
  }

  // ---- epilogue: bias + coalesced store via LDS bounce, 2 passes of 32 rows
  const int ch = idx[b];
  const float* bb = bias + (size_t)ch*OUTSZ;
  float bv[4];
  #pragma unroll
  for (int n = 0; n < 4; ++n) bv[n] = bb[wave*64 + n*16 + lo16];

  float* outb = out + ((size_t)b*SEQ + n0)*OUTSZ;
  #pragma unroll
  for (int p = 0; p < 2; ++p) {
    __syncthreads();   // previous LDS use done (A reads / prior pass reads)
    #pragma unroll
    for (int mm = 0; mm < 2; ++mm) {
      const int m = p*2 + mm;
      const int r = mm*16 + hi16*4;          // local row base (0..31)
      #pragma unroll
      for (int n = 0; n < 4; ++n) {
        const int col = wave*64 + n*16 + lo16;
        #pragma unroll
        for (int j = 0; j < 4; ++j)
          sm.e[(r + j)*260 + col] = acc[m][n][j] + bv[n];
      }
    }
    __syncthreads();
    // store: one full 1KB row per wave-instr (lane*16B), 8 rows per wave
    #pragma unroll
    for (int q = 0; q < 8; ++q) {
      const int rl = wave*8 + q;             // local row 0..31
      float4 v = *(const float4*)&sm.e[rl*260 + lane*4];
      *(float4*)(outb + (size_t)(p*32 + rl)*OUTSZ + lane*4) = v;
    }
  }
}

extern "C" void kernel_launch(void* const* d_in, const int* in_sizes, int n_in,
                              void* d_out, int out_size, void* d_ws, size_t ws_size,
                              hipStream_t stream) {
  const float* x    = (const float*)d_in[0];
  const int*   idx  = (const int*)d_in[1];
  const float* U    = (const float*)d_in[2];
  const float* V    = (const float*)d_in[3];
  const float* bias = (const float*)d_in[4];
  float* out  = (float*)d_out;
  ushort* wsW = (ushort*)d_ws;     // 256*65536*2 = 32 MiB

  synth_w<<<dim3(4, 256), 256, 0, stream>>>(U, V, idx, wsW);
  lr_gemm<<<8192, 256, 0, stream>>>(x, idx, bias, wsW, out);
}